// Round 9
// baseline (388.351 us; speedup 1.0000x reference)
//
#include <hip/hip_runtime.h>
#include <hip/hip_bf16.h>

#define Bb 128
#define LQ 32
#define LD 512
#define Hh 768
#define Cc 128

#define DBLOCKS ((Bb * LD) / 64)   // 1024 doc blocks (64 rows each)
#define QBLOCKS ((Bb * LQ) / 64)   // 64 query blocks

typedef short bf16x8 __attribute__((ext_vector_type(8)));
typedef short bf16x4 __attribute__((ext_vector_type(4)));
typedef float f32x4 __attribute__((ext_vector_type(4)));

__device__ __forceinline__ short f2bf(float f) {
  union { float f; unsigned u; } v;
  v.f = f;
  unsigned u = v.u + (0x7FFFu + ((v.u >> 16) & 1u));  // RNE
  return (short)(u >> 16);
}

__device__ __forceinline__ float b2f(short s) {
  union { unsigned u; float f; } v;
  v.u = ((unsigned)(unsigned short)s) << 16;
  return v.f;
}

// K0: W (H,C) fp32 -> Wt (C,H) bf16 (transposed so B fragments/chunks are
// row-contiguous).
__global__ __launch_bounds__(256) void k_wt(const float* __restrict__ W,
                                            short* __restrict__ Wt) {
  int idx = blockIdx.x * 256 + threadIdx.x;  // grid covers H*C exactly
  int h = idx >> 7;   // / 128
  int c = idx & 127;
  Wt[c * Hh + h] = f2bf(W[idx]);
}

// Query projection (R3-proven, verbatim): Y = qh @ W + b_comp, masked.
// 64 blocks, tile 64x128, BK=64, m97-style 2-barrier K-loop.
__global__ __launch_bounds__(256, 4) void k_proj_q(
    const float* __restrict__ qh, const short* __restrict__ Wt,
    const float* __restrict__ bcomp, const int* __restrict__ qmask,
    float* __restrict__ qv) {
  constexpr int ASTR = 144;
  constexpr int BSTR = 160;
  constexpr int ASZ = 64 * ASTR;     // 9 KB
  constexpr int BSZ = 128 * BSTR;    // 20 KB
  __shared__ __align__(16) char sm[ASZ + BSZ];

  const int tid = threadIdx.x;
  const int w = tid >> 6;
  const int lane = tid & 63;
  const int quad = lane >> 4;
  const int lm = lane & 15;

  const long row0b = (long)blockIdx.x * 64;

  const float* gA = qh + (row0b + w * 16 + (lane >> 4)) * (long)Hh + (lane & 15) * 4;
  const short* gB = Wt + (w * 32 + (lane >> 3)) * Hh + (lane & 7) * 8;
  const int aoff = (w * 16 + (lane >> 4)) * ASTR + (lane & 15) * 8;
  const int boff = (w * 32 + (lane >> 3)) * BSTR + (lane & 7) * 16;

  char* bufA = sm;
  char* bufB = sm + ASZ;

  f32x4 acc[8];
#pragma unroll
  for (int j = 0; j < 8; ++j) acc[j] = (f32x4){0.f, 0.f, 0.f, 0.f};

  float4 ar[4];
  bf16x8 br[4];
#pragma unroll
  for (int i = 0; i < 4; ++i) ar[i] = *(const float4*)(gA + i * 4 * Hh);
#pragma unroll
  for (int i = 0; i < 4; ++i) br[i] = *(const bf16x8*)(gB + i * 8 * Hh);

  for (int kk = 0; kk < Hh / 64; ++kk) {
    __syncthreads();
#pragma unroll
    for (int i = 0; i < 4; ++i) {
      bf16x4 p;
      p[0] = f2bf(ar[i].x); p[1] = f2bf(ar[i].y);
      p[2] = f2bf(ar[i].z); p[3] = f2bf(ar[i].w);
      *(bf16x4*)(bufA + aoff + i * 4 * ASTR) = p;
    }
#pragma unroll
    for (int i = 0; i < 4; ++i)
      *(bf16x8*)(bufB + boff + i * 8 * BSTR) = br[i];
    __syncthreads();

    {
      const long go = (kk + 1 < Hh / 64) ? (long)(kk + 1) * 64 : 0;
#pragma unroll
      for (int i = 0; i < 4; ++i) ar[i] = *(const float4*)(gA + i * 4 * Hh + go);
#pragma unroll
      for (int i = 0; i < 4; ++i) br[i] = *(const bf16x8*)(gB + i * 8 * Hh + go);
    }

#pragma unroll
    for (int ks = 0; ks < 2; ++ks) {
      bf16x8 fa = *(const bf16x8*)(bufA + (w * 16 + lm) * ASTR + ks * 64 + quad * 16);
#pragma unroll
      for (int j = 0; j < 8; ++j) {
        bf16x8 fb = *(const bf16x8*)(bufB + (j * 16 + lm) * BSTR + ks * 64 + quad * 16);
        acc[j] = __builtin_amdgcn_mfma_f32_16x16x32_bf16(fa, fb, acc[j], 0, 0, 0);
      }
    }
  }

  const long row0 = row0b + w * 16;
  float bc[8];
#pragma unroll
  for (int j = 0; j < 8; ++j) bc[j] = bcomp[j * 16 + lm];

#pragma unroll
  for (int r = 0; r < 4; ++r) {
    const long row = row0 + quad * 4 + r;
    const float scale = (float)qmask[row];
    float* yr = qv + row * Cc;
#pragma unroll
    for (int j = 0; j < 8; ++j) yr[j * 16 + lm] = (acc[j][r] + bc[j]) * scale;
  }
}

// Doc projection + importance + scores + partial max, ZERO-barrier K-loop.
// One block per (batch, 64-doc-token chunk); 4 waves, each owning a
// wave-PRIVATE 16-row A-strip in LDS.
//
// Why barrier-free is now legal (vs R5's failed de-staging): the K-loop
// barriers only ever protected the shared B-tile. Here B fragments stream
// DIRECTLY from the 192 KB L2-resident Wt -- per fb instruction the wave
// touches 16 FULLY-utilized 64B lines (col stride 1536 B, 4 quads x 16 B
// contiguous), unlike R5's A-gather (64 partial lines). A keeps its proven
// coalesced global->reg->LDS path, but the LDS strip is wave-private and
// per-wave DS ops execute in order -> no __syncthreads needed. With no
// barrier there is no vmcnt(0) drain, so the 2-deep A prefetch (R6's idea)
// actually survives: A(kk+2) issued at iter end, consumed 2 iters later
// (~2200 cyc cover > 900 cyc HBM latency).
//
// R8 post-mortem applied: q-fusion removed (its +48 VGPRs + the (256,4)
// 128-reg cap caused a 92 MB scratch-spill). Live set now ~100 regs.
// lq comes from k_proj_q's fp32 qv, converted to bf16 at staging (same one
// extra rounding as R8, which passed with absmax 4.0 unchanged).
//
// LDS (26880 B -> 4 blocks/CU at (256,4), whole 1024-block grid resident):
//   [0,    9216) : bufA (K-loop, wave-private strips)
//   after K-loop:  dvt bf16[64][136] @0 (17408), lqt bf16[32][136] @17408
//   [26112,26368) : dmsk[64]   [26368,26880) : pm[4][32]
__global__ __launch_bounds__(256, 4) void k_fused(
    const float* __restrict__ dh, const short* __restrict__ Wt,
    const float* __restrict__ qv, const float* __restrict__ bcomp,
    const int* __restrict__ dmask, const float* __restrict__ wstop,
    const float* __restrict__ bstop, float* __restrict__ partial) {
  constexpr int ASTR = 144;
  constexpr int SSTR = 136;          // bf16 row stride (272 B; 2-way max)
  constexpr int NK = Hh / 64;        // 12 K-chunks
  __shared__ __align__(16) char smem[26112 + 256 + 512];

  char* bufA = smem;
  short* dvt = (short*)smem;                   // [64][136] bf16, after GEMM
  short* lqt = (short*)(smem + 17408);         // [32][136] bf16, after GEMM
  int* dmsk = (int*)(smem + 26112);            // [64]
  float* pm = (float*)(smem + 26112 + 256);    // [4][32]

  const int tid = threadIdx.x;
  const int w = tid >> 6;
  const int lane = tid & 63;
  const int quad = lane >> 4;
  const int lm = lane & 15;

  const int b = blockIdx.x >> 3;     // batch
  const int chunk = blockIdx.x & 7;  // 64-token chunk within doc
  const long row0b = (long)b * LD + chunk * 64;

  if (tid < 64) dmsk[tid] = dmask[row0b + tid];

  // A: coalesced staging loads (4 instrs x 4 rows x 256 B contiguous).
  const float* gA = dh + (row0b + w * 16 + (lane >> 4)) * (long)Hh + (lane & 15) * 4;
  // B fragment base: lane (quad,lm) reads Wt[col J*16+lm][k..k+7] bf16x8;
  // per-j offset j*16*Hh is wave-uniform (folds to scalar base).
  const short* gB = Wt + lm * Hh + quad * 8;
  const int aoff = (w * 16 + (lane >> 4)) * ASTR + (lane & 15) * 8;

  f32x4 acc[8];
#pragma unroll
  for (int j = 0; j < 8; ++j) acc[j] = (f32x4){0.f, 0.f, 0.f, 0.f};

  float4 arA[4], arB[4];
  // 2-deep preload: chunks 0 and 1.
#pragma unroll
  for (int i = 0; i < 4; ++i) arA[i] = *(const float4*)(gA + i * 4 * Hh);
#pragma unroll
  for (int i = 0; i < 4; ++i) arB[i] = *(const float4*)(gA + 64 + i * 4 * Hh);

  // One K-iteration on the wave's private strip. ar holds chunk kk; refilled
  // with chunk kk+2. No barriers: per-wave DS ops are in-order, strip is
  // private, B comes from L2.
  auto iter = [&](int kk, float4 (&ar)[4]) {
    // pack chunk kk -> private LDS strip (vmcnt waits only this ar group)
#pragma unroll
    for (int i = 0; i < 4; ++i) {
      bf16x4 p;
      p[0] = f2bf(ar[i].x); p[1] = f2bf(ar[i].y);
      p[2] = f2bf(ar[i].z); p[3] = f2bf(ar[i].w);
      *(bf16x4*)(bufA + aoff + i * 4 * ASTR) = p;
    }
    // compute: fa from private strip, fb direct from Wt (L2)
#pragma unroll
    for (int ks = 0; ks < 2; ++ks) {
      bf16x8 fa = *(const bf16x8*)(bufA + (w * 16 + lm) * ASTR + ks * 64 + quad * 16);
      bf16x8 fbv[8];
#pragma unroll
      for (int j = 0; j < 8; ++j)
        fbv[j] = *(const bf16x8*)(gB + j * 16 * Hh + kk * 64 + ks * 32);
#pragma unroll
      for (int j = 0; j < 8; ++j)
        acc[j] = __builtin_amdgcn_mfma_f32_16x16x32_bf16(fa, fbv[j], acc[j], 0, 0, 0);
    }
    // 2-deep A prefetch (no barrier drain anywhere -> stays in flight)
    const long go = (kk + 2 < NK) ? (long)(kk + 2) * 64 : 0;
#pragma unroll
    for (int i = 0; i < 4; ++i)
      ar[i] = *(const float4*)(gA + go + i * 4 * Hh);
  };

  for (int kp = 0; kp < NK / 2; ++kp) {
    iter(2 * kp, arA);
    iter(2 * kp + 1, arB);
  }

  __syncthreads();  // all waves done; dmsk visible; staging area dead

  // Stage lq: qv fp32 (L2-hot, written by k_proj_q) -> lqt bf16.
  // Loads issued first; dvt math below covers their latency.
  {
    const float4* src = (const float4*)(qv + (size_t)b * LQ * Cc);
    float4 t[4];
#pragma unroll
    for (int k = 0; k < 4; ++k) t[k] = src[tid + k * 256];
#pragma unroll
    for (int k = 0; k < 4; ++k) {
      const int i = tid + k * 256;
      const int q = i >> 5;
      const int c = (i & 31) << 2;
      bf16x4 p;
      p[0] = f2bf(t[k].x); p[1] = f2bf(t[k].y);
      p[2] = f2bf(t[k].z); p[3] = f2bf(t[k].w);
      *(bf16x4*)&lqt[q * SSTR + c] = p;
    }
  }

  // Epilogue: bias, importance (quad butterfly, fp32), mask -> dvt bf16.
  float bc[8], wsv[8];
#pragma unroll
  for (int j = 0; j < 8; ++j) bc[j] = bcomp[j * 16 + lm];
#pragma unroll
  for (int j = 0; j < 8; ++j) wsv[j] = wstop[j * 16 + lm];
  const float bs = bstop[0];

#pragma unroll
  for (int r = 0; r < 4; ++r) {
    const int lrow = w * 16 + quad * 4 + r;  // chunk-local doc row
    float v[8];
#pragma unroll
    for (int j = 0; j < 8; ++j) v[j] = acc[j][r] + bc[j];
    float p = 0.f;
#pragma unroll
    for (int j = 0; j < 8; ++j) p += v[j] * wsv[j];
    p += __shfl_xor(p, 1);
    p += __shfl_xor(p, 2);
    p += __shfl_xor(p, 4);
    p += __shfl_xor(p, 8);
    const float imp = fmaxf(p + bs, 0.f);
    const float scale = imp * (float)dmsk[lrow];
#pragma unroll
    for (int j = 0; j < 8; ++j)
      dvt[lrow * SSTR + j * 16 + lm] = f2bf(v[j] * scale);
  }
  __syncthreads();  // dvt + lqt visible

  // Score phase (R8-proven): thread (qt,kt) owns q rows {qt,qt+16} x doc
  // rows kt*4..+3; bf16x8 LDS reads, shift-convert, fp32 FMA accumulate.
  const int qt = tid & 15;
  const int kt = tid >> 4;
  const int kbase = kt * 4;
  float a[2][4];
#pragma unroll
  for (int qi = 0; qi < 2; ++qi)
#pragma unroll
    for (int ki = 0; ki < 4; ++ki) a[qi][ki] = 0.f;

  for (int c = 0; c < Cc; c += 8) {
    bf16x8 q0 = *(const bf16x8*)&lqt[qt * SSTR + c];
    bf16x8 q1 = *(const bf16x8*)&lqt[(qt + 16) * SSTR + c];
    bf16x8 d0 = *(const bf16x8*)&dvt[(kbase + 0) * SSTR + c];
    bf16x8 d1 = *(const bf16x8*)&dvt[(kbase + 1) * SSTR + c];
    bf16x8 d2 = *(const bf16x8*)&dvt[(kbase + 2) * SSTR + c];
    bf16x8 d3 = *(const bf16x8*)&dvt[(kbase + 3) * SSTR + c];
#pragma unroll
    for (int e = 0; e < 8; ++e) {
      const float f0 = b2f(q0[e]);
      const float f1 = b2f(q1[e]);
      const float g0 = b2f(d0[e]);
      const float g1 = b2f(d1[e]);
      const float g2 = b2f(d2[e]);
      const float g3 = b2f(d3[e]);
      a[0][0] += f0 * g0; a[0][1] += f0 * g1;
      a[0][2] += f0 * g2; a[0][3] += f0 * g3;
      a[1][0] += f1 * g0; a[1][1] += f1 * g1;
      a[1][2] += f1 * g2; a[1][3] += f1 * g3;
    }
  }
  float m0 = -1000.f, m1 = -1000.f;
#pragma unroll
  for (int ki = 0; ki < 4; ++ki) {
    if (dmsk[kbase + ki]) {
      m0 = fmaxf(m0, a[0][ki]);
      m1 = fmaxf(m1, a[1][ki]);
    }
  }
  // Reduce over the wave's 4 kt groups (lanes differ in bits 4-5).
  m0 = fmaxf(m0, __shfl_xor(m0, 16));
  m0 = fmaxf(m0, __shfl_xor(m0, 32));
  m1 = fmaxf(m1, __shfl_xor(m1, 16));
  m1 = fmaxf(m1, __shfl_xor(m1, 32));
  if (lane < 16) {
    pm[w * 32 + lane] = m0;        // q row = lane
    pm[w * 32 + lane + 16] = m1;   // q row = lane + 16
  }
  __syncthreads();
  if (tid < LQ) {
    float mx = fmaxf(fmaxf(pm[tid], pm[32 + tid]),
                     fmaxf(pm[64 + tid], pm[96 + tid]));
    partial[((size_t)b * LQ + tid) * 8 + chunk] = mx;
  }
}

// Finalize: cls dot on raw CLS vectors, max over chunks, masked sum, merge.
__global__ __launch_bounds__(256) void k_final(
    const float* __restrict__ qh, const float* __restrict__ dh,
    const int* __restrict__ qmask, const float* __restrict__ partial,
    const float* __restrict__ merger, float* __restrict__ out) {
  const int b = blockIdx.x;
  const int tid = threadIdx.x;
  __shared__ float red[256];
  __shared__ float clss;
  const float* qc = qh + (size_t)b * LQ * Hh;  // q row 0 = CLS
  const float* dc = dh + (size_t)b * LD * Hh;  // d row 0 = CLS
  float s = 0.f;
  for (int h = tid; h < Hh; h += 256) s += qc[h] * dc[h];
  red[tid] = s;
  __syncthreads();
  for (int off = 128; off > 0; off >>= 1) {
    if (tid < off) red[tid] += red[tid + off];
    __syncthreads();
  }
  if (tid == 0) clss = red[0];
  __syncthreads();
  float t = 0.f;
  if (tid < LQ) {
    const float* pp = partial + ((size_t)b * LQ + tid) * 8;
    float mx = pp[0];
#pragma unroll
    for (int c = 1; c < 8; ++c) mx = fmaxf(mx, pp[c]);
    if (qmask[b * LQ + tid]) t = mx;
  }
  red[tid] = t;
  __syncthreads();
  for (int off = 128; off > 0; off >>= 1) {
    if (tid < off) red[tid] += red[tid + off];
    __syncthreads();
  }
  if (tid == 0) {
    float w = 1.f / (1.f + expf(-merger[0]));
    float cs = clss * w;
    float ts = red[0] * (1.f - w);
    out[b] = cs + ts;        // score
    out[Bb + b] = cs;        // cls_score
    out[2 * Bb + b] = ts;    // term_score
  }
}

extern "C" void kernel_launch(void* const* d_in, const int* in_sizes, int n_in,
                              void* d_out, int out_size, void* d_ws, size_t ws_size,
                              hipStream_t stream) {
  const float* qh  = (const float*)d_in[0];  // (B,LQ,H)
  const float* dh  = (const float*)d_in[1];  // (B,LD,H)
  const int*   qm  = (const int*)d_in[2];    // (B,LQ)
  const int*   dm  = (const int*)d_in[3];    // (B,LD)
  const float* W   = (const float*)d_in[4];  // (H,C)
  const float* bc  = (const float*)d_in[5];  // (C)
  const float* wst = (const float*)d_in[6];  // (C,1)
  const float* bst = (const float*)d_in[7];  // (1)
  const float* mrg = (const float*)d_in[8];  // (1)
  float* out = (float*)d_out;                // 3*B floats

  char* ws = (char*)d_ws;
  short* Wt  = (short*)ws;                       // 192 KB bf16 W^T
  float* qv  = (float*)(ws + 196608);            // 2 MB q_vecs fp32
  float* prt = (float*)(ws + 196608 + 2097152);  // 128 KB partial max

  k_wt<<<(Hh * Cc) / 256, 256, 0, stream>>>(W, Wt);
  k_proj_q<<<QBLOCKS, 256, 0, stream>>>(qh, Wt, bc, qm, qv);
  k_fused<<<DBLOCKS, 256, 0, stream>>>(dh, Wt, qv, bc, dm, wst, bst, prt);
  k_final<<<Bb, 256, 0, stream>>>(qh, dh, qm, prt, mrg, out);
}

// Round 10
// 326.810 us; speedup vs baseline: 1.1883x; 1.1883x over previous
//
#include <hip/hip_runtime.h>
#include <hip/hip_bf16.h>

#define Bb 128
#define LQ 32
#define LD 512
#define Hh 768
#define Cc 128

#define DBLOCKS ((Bb * LD) / 64)   // 1024 doc blocks (64 rows each)
#define QBLOCKS ((Bb * LQ) / 64)   // 64 query blocks

typedef short bf16x8 __attribute__((ext_vector_type(8)));
typedef short bf16x4 __attribute__((ext_vector_type(4)));
typedef float f32x4 __attribute__((ext_vector_type(4)));

__device__ __forceinline__ short f2bf(float f) {
  union { float f; unsigned u; } v;
  v.f = f;
  unsigned u = v.u + (0x7FFFu + ((v.u >> 16) & 1u));  // RNE
  return (short)(u >> 16);
}

__device__ __forceinline__ float b2f(short s) {
  union { unsigned u; float f; } v;
  v.u = ((unsigned)(unsigned short)s) << 16;
  return v.f;
}

// K0: W (H,C) fp32 -> Wt (C,H) bf16 (transposed so B-chunks are row-contiguous)
__global__ __launch_bounds__(256) void k_wt(const float* __restrict__ W,
                                            short* __restrict__ Wt) {
  int idx = blockIdx.x * 256 + threadIdx.x;  // grid covers H*C exactly
  int h = idx >> 7;   // / 128
  int c = idx & 127;
  Wt[c * Hh + h] = f2bf(W[idx]);
}

// Query projection (R3-proven, verbatim): Y = qh @ W + b_comp, masked.
// 64 blocks, tile 64x128, BK=64, m97-style 2-barrier K-loop.
__global__ __launch_bounds__(256, 4) void k_proj_q(
    const float* __restrict__ qh, const short* __restrict__ Wt,
    const float* __restrict__ bcomp, const int* __restrict__ qmask,
    float* __restrict__ qv) {
  constexpr int ASTR = 144;
  constexpr int BSTR = 160;
  constexpr int ASZ = 64 * ASTR;     // 9 KB
  constexpr int BSZ = 128 * BSTR;    // 20 KB
  __shared__ __align__(16) char sm[ASZ + BSZ];

  const int tid = threadIdx.x;
  const int w = tid >> 6;
  const int lane = tid & 63;
  const int quad = lane >> 4;
  const int lm = lane & 15;

  const long row0b = (long)blockIdx.x * 64;

  const float* gA = qh + (row0b + w * 16 + (lane >> 4)) * (long)Hh + (lane & 15) * 4;
  const short* gB = Wt + (w * 32 + (lane >> 3)) * Hh + (lane & 7) * 8;
  const int aoff = (w * 16 + (lane >> 4)) * ASTR + (lane & 15) * 8;
  const int boff = (w * 32 + (lane >> 3)) * BSTR + (lane & 7) * 16;

  char* bufA = sm;
  char* bufB = sm + ASZ;

  f32x4 acc[8];
#pragma unroll
  for (int j = 0; j < 8; ++j) acc[j] = (f32x4){0.f, 0.f, 0.f, 0.f};

  float4 ar[4];
  bf16x8 br[4];
#pragma unroll
  for (int i = 0; i < 4; ++i) ar[i] = *(const float4*)(gA + i * 4 * Hh);
#pragma unroll
  for (int i = 0; i < 4; ++i) br[i] = *(const bf16x8*)(gB + i * 8 * Hh);

  for (int kk = 0; kk < Hh / 64; ++kk) {
    __syncthreads();
#pragma unroll
    for (int i = 0; i < 4; ++i) {
      bf16x4 p;
      p[0] = f2bf(ar[i].x); p[1] = f2bf(ar[i].y);
      p[2] = f2bf(ar[i].z); p[3] = f2bf(ar[i].w);
      *(bf16x4*)(bufA + aoff + i * 4 * ASTR) = p;
    }
#pragma unroll
    for (int i = 0; i < 4; ++i)
      *(bf16x8*)(bufB + boff + i * 8 * BSTR) = br[i];
    __syncthreads();

    {
      const long go = (kk + 1 < Hh / 64) ? (long)(kk + 1) * 64 : 0;
#pragma unroll
      for (int i = 0; i < 4; ++i) ar[i] = *(const float4*)(gA + i * 4 * Hh + go);
#pragma unroll
      for (int i = 0; i < 4; ++i) br[i] = *(const bf16x8*)(gB + i * 8 * Hh + go);
    }

#pragma unroll
    for (int ks = 0; ks < 2; ++ks) {
      bf16x8 fa = *(const bf16x8*)(bufA + (w * 16 + lm) * ASTR + ks * 64 + quad * 16);
#pragma unroll
      for (int j = 0; j < 8; ++j) {
        bf16x8 fb = *(const bf16x8*)(bufB + (j * 16 + lm) * BSTR + ks * 64 + quad * 16);
        acc[j] = __builtin_amdgcn_mfma_f32_16x16x32_bf16(fa, fb, acc[j], 0, 0, 0);
      }
    }
  }

  const long row0 = row0b + w * 16;
  float bc[8];
#pragma unroll
  for (int j = 0; j < 8; ++j) bc[j] = bcomp[j * 16 + lm];

#pragma unroll
  for (int r = 0; r < 4; ++r) {
    const long row = row0 + quad * 4 + r;
    const float scale = (float)qmask[row];
    float* yr = qv + row * Cc;
#pragma unroll
    for (int j = 0; j < 8; ++j) yr[j * 16 + lm] = (acc[j][r] + bc[j]) * scale;
  }
}

// Doc projection + importance + scores + partial max.
// SINGLE controlled change vs the R3-proven version (331.3 total, k_doc =
// 117 us @ 25% occupancy): the score tiles (dvt/lqt) are stored as bf16
// and packed into the DEAD GEMM-staging union, shrinking LDS 53.0 ->
// 30.5 KB => 5 blocks/CU at __launch_bounds__(256,5) (VGPR cap 102; K-loop
// live set ~76, R3 measured 68 -- no spill risk, unlike R8's q-fused 128-cap
// spill). K-loop is R3's verbatim: __syncthreads staging, shared-B LDS tile,
// 1-deep prefetch -- every scheduling "improvement" tried on it (R5 gather,
// R6/R7 raw-barrier deep prefetch, R9 zero-barrier B-from-L2) regressed or
// tied; cross-block TLP is the one lever with direct counter support
// (R8: occupancy 25->43% when LDS shrank).
// bf16 score-dot rounding was harness-proven in R8/R9 (absmax 4.0).
//
// LDS layout (30464 B total):
//   [0,     29696) : GEMM staging (A 9216 @ASTR 144 + B 20480 @BSTR 160)
//                    -- after K-loop: dvt bf16[64][136] @0 (17408 B),
//                                     lqt bf16[32][136] @17408 (8704 B)
//   [29696, 29952) : dmsk[64]
//   [29952, 30464) : pm[4][32] f32 (per-wave maxima)
__global__ __launch_bounds__(256, 5) void k_doc(
    const float* __restrict__ dh, const short* __restrict__ Wt,
    const float* __restrict__ qv, const float* __restrict__ bcomp,
    const int* __restrict__ dmask, const float* __restrict__ wstop,
    const float* __restrict__ bstop, float* __restrict__ partial) {
  constexpr int ASTR = 144;
  constexpr int BSTR = 160;
  constexpr int ASZ = 64 * ASTR;     // 9216
  constexpr int SSTR = 136;          // bf16 row stride (272 B; 2-way max)
  constexpr int NK = Hh / 64;        // 12 K-chunks
  __shared__ __align__(16) char smem[29696 + 256 + 512];

  char* bufA = smem;
  char* bufB = smem + ASZ;
  short* dvt = (short*)smem;                   // [64][136] bf16, after GEMM
  short* lqt = (short*)(smem + 17408);         // [32][136] bf16, after GEMM
  int* dmsk = (int*)(smem + 29696);            // [64]
  float* pm = (float*)(smem + 29696 + 256);    // [4][32]

  const int tid = threadIdx.x;
  const int w = tid >> 6;
  const int lane = tid & 63;
  const int quad = lane >> 4;
  const int lm = lane & 15;

  const int b = blockIdx.x >> 3;     // batch
  const int chunk = blockIdx.x & 7;  // 64-token chunk within doc
  const long row0b = (long)b * LD + chunk * 64;

  if (tid < 64) dmsk[tid] = dmask[row0b + tid];

  const float* gA = dh + (row0b + w * 16 + (lane >> 4)) * (long)Hh + (lane & 15) * 4;
  const short* gB = Wt + (w * 32 + (lane >> 3)) * Hh + (lane & 7) * 8;
  const int aoff = (w * 16 + (lane >> 4)) * ASTR + (lane & 15) * 8;
  const int boff = (w * 32 + (lane >> 3)) * BSTR + (lane & 7) * 16;

  f32x4 acc[8];
#pragma unroll
  for (int j = 0; j < 8; ++j) acc[j] = (f32x4){0.f, 0.f, 0.f, 0.f};

  float4 ar[4];
  bf16x8 br[4];
  // preload chunk 0
#pragma unroll
  for (int i = 0; i < 4; ++i) ar[i] = *(const float4*)(gA + i * 4 * Hh);
#pragma unroll
  for (int i = 0; i < 4; ++i) br[i] = *(const bf16x8*)(gB + i * 8 * Hh);

  for (int kk = 0; kk < NK; ++kk) {
    __syncthreads();  // previous chunk's readers done
    // pack + write chunk kk regs -> LDS
#pragma unroll
    for (int i = 0; i < 4; ++i) {
      bf16x4 p;
      p[0] = f2bf(ar[i].x); p[1] = f2bf(ar[i].y);
      p[2] = f2bf(ar[i].z); p[3] = f2bf(ar[i].w);
      *(bf16x4*)(bufA + aoff + i * 4 * ASTR) = p;
    }
#pragma unroll
    for (int i = 0; i < 4; ++i)
      *(bf16x8*)(bufB + boff + i * 8 * BSTR) = br[i];
    __syncthreads();  // LDS tile visible

    // issue next-chunk global loads; they have the whole compute phase to land
    {
      const long go = (kk + 1 < NK) ? (long)(kk + 1) * 64 : 0;
#pragma unroll
      for (int i = 0; i < 4; ++i) ar[i] = *(const float4*)(gA + i * 4 * Hh + go);
#pragma unroll
      for (int i = 0; i < 4; ++i) br[i] = *(const bf16x8*)(gB + i * 8 * Hh + go);
    }

    // compute chunk kk: wave tile 16 rows x 128 cols, 2 k-steps of 32
#pragma unroll
    for (int ks = 0; ks < 2; ++ks) {
      bf16x8 fa = *(const bf16x8*)(bufA + (w * 16 + lm) * ASTR + ks * 64 + quad * 16);
#pragma unroll
      for (int j = 0; j < 8; ++j) {
        bf16x8 fb = *(const bf16x8*)(bufB + (j * 16 + lm) * BSTR + ks * 64 + quad * 16);
        acc[j] = __builtin_amdgcn_mfma_f32_16x16x32_bf16(fa, fb, acc[j], 0, 0, 0);
      }
    }
  }

  __syncthreads();  // all staging reads done -> safe to overwrite with dv/lq

  // Stage lq: qv fp32 (L2-hot, written by k_proj_q) -> lqt bf16.
  // Loads issued first; the dvt epilogue math below covers their latency.
  {
    const float4* src = (const float4*)(qv + (size_t)b * LQ * Cc);
    float4 t[4];
#pragma unroll
    for (int k = 0; k < 4; ++k) t[k] = src[tid + k * 256];
#pragma unroll
    for (int k = 0; k < 4; ++k) {
      const int i = tid + k * 256;
      const int q = i >> 5;
      const int c = (i & 31) << 2;
      bf16x4 p;
      p[0] = f2bf(t[k].x); p[1] = f2bf(t[k].y);
      p[2] = f2bf(t[k].z); p[3] = f2bf(t[k].w);
      *(bf16x4*)&lqt[q * SSTR + c] = p;
    }
  }

  // Epilogue: bias, importance (quad butterfly, fp32), mask -> dvt bf16.
  float bc[8], wsv[8];
#pragma unroll
  for (int j = 0; j < 8; ++j) bc[j] = bcomp[j * 16 + lm];
#pragma unroll
  for (int j = 0; j < 8; ++j) wsv[j] = wstop[j * 16 + lm];
  const float bs = bstop[0];

#pragma unroll
  for (int r = 0; r < 4; ++r) {
    const int lrow = w * 16 + quad * 4 + r;  // chunk-local doc row
    float v[8];
#pragma unroll
    for (int j = 0; j < 8; ++j) v[j] = acc[j][r] + bc[j];
    float p = 0.f;
#pragma unroll
    for (int j = 0; j < 8; ++j) p += v[j] * wsv[j];
    p += __shfl_xor(p, 1);
    p += __shfl_xor(p, 2);
    p += __shfl_xor(p, 4);
    p += __shfl_xor(p, 8);
    const float imp = fmaxf(p + bs, 0.f);
    const float scale = imp * (float)dmsk[lrow];
#pragma unroll
    for (int j = 0; j < 8; ++j)
      dvt[lrow * SSTR + j * 16 + lm] = f2bf(v[j] * scale);
  }
  __syncthreads();  // dvt + lqt visible

  // Score phase (R8/R9-proven): thread (qt,kt) owns q rows {qt,qt+16} x doc
  // rows kt*4..+3; bf16x8 LDS reads, shift-convert, fp32 FMA accumulate.
  const int qt = tid & 15;
  const int kt = tid >> 4;
  const int kbase = kt * 4;
  float a[2][4];
#pragma unroll
  for (int qi = 0; qi < 2; ++qi)
#pragma unroll
    for (int ki = 0; ki < 4; ++ki) a[qi][ki] = 0.f;

  for (int c = 0; c < Cc; c += 8) {
    bf16x8 q0 = *(const bf16x8*)&lqt[qt * SSTR + c];
    bf16x8 q1 = *(const bf16x8*)&lqt[(qt + 16) * SSTR + c];
    bf16x8 d0 = *(const bf16x8*)&dvt[(kbase + 0) * SSTR + c];
    bf16x8 d1 = *(const bf16x8*)&dvt[(kbase + 1) * SSTR + c];
    bf16x8 d2 = *(const bf16x8*)&dvt[(kbase + 2) * SSTR + c];
    bf16x8 d3 = *(const bf16x8*)&dvt[(kbase + 3) * SSTR + c];
#pragma unroll
    for (int e = 0; e < 8; ++e) {
      const float f0 = b2f(q0[e]);
      const float f1 = b2f(q1[e]);
      const float g0 = b2f(d0[e]);
      const float g1 = b2f(d1[e]);
      const float g2 = b2f(d2[e]);
      const float g3 = b2f(d3[e]);
      a[0][0] += f0 * g0; a[0][1] += f0 * g1;
      a[0][2] += f0 * g2; a[0][3] += f0 * g3;
      a[1][0] += f1 * g0; a[1][1] += f1 * g1;
      a[1][2] += f1 * g2; a[1][3] += f1 * g3;
    }
  }
  float m0 = -1000.f, m1 = -1000.f;
#pragma unroll
  for (int ki = 0; ki < 4; ++ki) {
    if (dmsk[kbase + ki]) {
      m0 = fmaxf(m0, a[0][ki]);
      m1 = fmaxf(m1, a[1][ki]);
    }
  }
  // Reduce over the wave's 4 kt groups (lanes differ in bits 4-5).
  m0 = fmaxf(m0, __shfl_xor(m0, 16));
  m0 = fmaxf(m0, __shfl_xor(m0, 32));
  m1 = fmaxf(m1, __shfl_xor(m1, 16));
  m1 = fmaxf(m1, __shfl_xor(m1, 32));
  if (lane < 16) {
    pm[w * 32 + lane] = m0;        // q row = lane
    pm[w * 32 + lane + 16] = m1;   // q row = lane + 16
  }
  __syncthreads();
  if (tid < LQ) {
    float mx = fmaxf(fmaxf(pm[tid], pm[32 + tid]),
                     fmaxf(pm[64 + tid], pm[96 + tid]));
    partial[((size_t)b * LQ + tid) * 8 + chunk] = mx;
  }
}

// Finalize: cls dot on raw CLS vectors, max over chunks, masked sum, merge.
__global__ __launch_bounds__(256) void k_final(
    const float* __restrict__ qh, const float* __restrict__ dh,
    const int* __restrict__ qmask, const float* __restrict__ partial,
    const float* __restrict__ merger, float* __restrict__ out) {
  const int b = blockIdx.x;
  const int tid = threadIdx.x;
  __shared__ float red[256];
  __shared__ float clss;
  const float* qc = qh + (size_t)b * LQ * Hh;  // q row 0 = CLS
  const float* dc = dh + (size_t)b * LD * Hh;  // d row 0 = CLS
  float s = 0.f;
  for (int h = tid; h < Hh; h += 256) s += qc[h] * dc[h];
  red[tid] = s;
  __syncthreads();
  for (int off = 128; off > 0; off >>= 1) {
    if (tid < off) red[tid] += red[tid + off];
    __syncthreads();
  }
  if (tid == 0) clss = red[0];
  __syncthreads();
  float t = 0.f;
  if (tid < LQ) {
    const float* pp = partial + ((size_t)b * LQ + tid) * 8;
    float mx = pp[0];
#pragma unroll
    for (int c = 1; c < 8; ++c) mx = fmaxf(mx, pp[c]);
    if (qmask[b * LQ + tid]) t = mx;
  }
  red[tid] = t;
  __syncthreads();
  for (int off = 128; off > 0; off >>= 1) {
    if (tid < off) red[tid] += red[tid + off];
    __syncthreads();
  }
  if (tid == 0) {
    float w = 1.f / (1.f + expf(-merger[0]));
    float cs = clss * w;
    float ts = red[0] * (1.f - w);
    out[b] = cs + ts;        // score
    out[Bb + b] = cs;        // cls_score
    out[2 * Bb + b] = ts;    // term_score
  }
}

extern "C" void kernel_launch(void* const* d_in, const int* in_sizes, int n_in,
                              void* d_out, int out_size, void* d_ws, size_t ws_size,
                              hipStream_t stream) {
  const float* qh  = (const float*)d_in[0];  // (B,LQ,H)
  const float* dh  = (const float*)d_in[1];  // (B,LD,H)
  const int*   qm  = (const int*)d_in[2];    // (B,LQ)
  const int*   dm  = (const int*)d_in[3];    // (B,LD)
  const float* W   = (const float*)d_in[4];  // (H,C)
  const float* bc  = (const float*)d_in[5];  // (C)
  const float* wst = (const float*)d_in[6];  // (C,1)
  const float* bst = (const float*)d_in[7];  // (1)
  const float* mrg = (const float*)d_in[8];  // (1)
  float* out = (float*)d_out;                // 3*B floats

  char* ws = (char*)d_ws;
  short* Wt  = (short*)ws;                       // 192 KB bf16 W^T
  float* qv  = (float*)(ws + 196608);            // 2 MB q_vecs fp32
  float* prt = (float*)(ws + 196608 + 2097152);  // 128 KB partial max

  k_wt<<<(Hh * Cc) / 256, 256, 0, stream>>>(W, Wt);
  k_proj_q<<<QBLOCKS, 256, 0, stream>>>(qh, Wt, bc, qm, qv);
  k_doc<<<DBLOCKS, 256, 0, stream>>>(dh, Wt, qv, bc, dm, wst, bst, prt);
  k_final<<<Bb, 256, 0, stream>>>(qh, dh, qm, prt, mrg, out);
}

// Round 12
// 319.725 us; speedup vs baseline: 1.2146x; 1.0222x over previous
//
#include <hip/hip_runtime.h>
#include <hip/hip_bf16.h>

#define Bb 128
#define LQ 32
#define LD 512
#define Hh 768
#define Cc 128

#define DBLOCKS ((Bb * LD) / 64)   // 1024 doc blocks (64 rows each)

typedef short bf16x8 __attribute__((ext_vector_type(8)));
typedef short bf16x4 __attribute__((ext_vector_type(4)));
typedef float f32x4 __attribute__((ext_vector_type(4)));

__device__ __forceinline__ short f2bf(float f) {
  union { float f; unsigned u; } v;
  v.f = f;
  unsigned u = v.u + (0x7FFFu + ((v.u >> 16) & 1u));  // RNE
  return (short)(u >> 16);
}

__device__ __forceinline__ float b2f(short s) {
  union { unsigned u; float f; } v;
  v.u = ((unsigned)(unsigned short)s) << 16;
  return v.f;
}

// K0: W (H,C) fp32 -> Wt (C,H) bf16 (transposed so B-chunks are row-contiguous)
__global__ __launch_bounds__(256) void k_wt(const float* __restrict__ W,
                                            short* __restrict__ Wt) {
  int idx = blockIdx.x * 256 + threadIdx.x;  // grid covers H*C exactly
  int h = idx >> 7;   // / 128
  int c = idx & 127;
  Wt[c * Hh + h] = f2bf(W[idx]);
}

// Fully fused doc+query projection + importance + scores + partial max.
// One block per (batch, 64-doc-token chunk).
//
// R11 post-mortem (absmax 328): the q-MFMA sat under a divergent guard
// `if ((j>>2)==wc) accq[..] = mfma(..)`. MFMA is wave-cooperative and does
// NOT honor per-lane EXEC like plain VALU; for a 1-instruction guarded
// block the compiler can elide the s_cbranch_execz skip-branch, so the
// MFMA executed even on guard-false waves -> every wave accumulated BOTH
// column halves into accq[0..3] (j and j+4 alias) -> lqt ~ qv[c]+qv[c+-64].
// R4/R8 passed with the same-shaped `if (isq)` guard only because their
// guard-false waves never STORED accq (stores do respect EXEC).
// RULE: never put MFMA under a non-provably-uniform guard.
//
// Fix: q-MFMAs are UNCONDITIONAL -- each wave issues exactly 4 per ks,
// reading fb again at its wave-uniform column base wc*64 (8 extra
// ds_read_b128 per K-chunk, ~2% DS traffic). Per-output accumulation order
// identical to R4/R8 -> bit-identical q_vecs.
//
// Structure otherwise = R10 (proven) + 4-way q-split:
//   wave w: q rows (w&1)*16..+15 x cols (w>>1)*64..+63; accq = 16 AGPRs.
//   Budget at the (256,4) 128-reg cap: 32(acc)+16(accq) AGPR + ~75 arch.
//
// LDS layout (30464 B; 4 blocks/CU by VGPR, grid 1024 all-resident):
//   [0,     29696) : GEMM staging (A 9216 @144 + B 20480 @160)
//                    -- after K-loop: dvt bf16[64][136] @0 (17408 B),
//                                     lqt bf16[32][136] @17408 (8704 B)
//   [29696, 29952) : dmsk[64]
//   [29952, 30464) : pm[4][32] f32
__global__ __launch_bounds__(256, 4) void k_doc(
    const float* __restrict__ dh, const float* __restrict__ qh,
    const short* __restrict__ Wt, const float* __restrict__ bcomp,
    const int* __restrict__ qmask, const int* __restrict__ dmask,
    const float* __restrict__ wstop, const float* __restrict__ bstop,
    float* __restrict__ partial) {
  constexpr int ASTR = 144;
  constexpr int BSTR = 160;
  constexpr int ASZ = 64 * ASTR;     // 9216
  constexpr int SSTR = 136;          // bf16 row stride (272 B; 2-way max)
  constexpr int NK = Hh / 64;        // 12 K-chunks
  __shared__ __align__(16) char smem[29696 + 256 + 512];

  char* bufA = smem;
  char* bufB = smem + ASZ;
  short* dvt = (short*)smem;                   // [64][136] bf16, after GEMM
  short* lqt = (short*)(smem + 17408);         // [32][136] bf16, after GEMM
  int* dmsk = (int*)(smem + 29696);            // [64]
  float* pm = (float*)(smem + 29696 + 256);    // [4][32]

  const int tid = threadIdx.x;
  const int w = tid >> 6;
  const int lane = tid & 63;
  const int quad = lane >> 4;
  const int lm = lane & 15;
  const int wq = w & 1;   // q row half: rows wq*16..+15
  const int wc = w >> 1;  // q col half: cols wc*64..+63

  const int b = blockIdx.x >> 3;     // batch
  const int chunk = blockIdx.x & 7;  // 64-token chunk within doc
  const long row0b = (long)b * LD + chunk * 64;

  if (tid < 64) dmsk[tid] = dmask[row0b + tid];

  const float* gA = dh + (row0b + w * 16 + (lane >> 4)) * (long)Hh + (lane & 15) * 4;
  const short* gB = Wt + (w * 32 + (lane >> 3)) * Hh + (lane & 7) * 8;
  const float* gQ = qh + ((long)b * LQ + wq * 16 + lm) * (long)Hh + quad * 8;
  const int aoff = (w * 16 + (lane >> 4)) * ASTR + (lane & 15) * 8;
  const int boff = (w * 32 + (lane >> 3)) * BSTR + (lane & 7) * 16;
  // Wave-uniform q-column base inside bufB: rows wc*64.. of the B tile.
  const int qboff = (wc * 64 + lm) * BSTR;

  f32x4 acc[8], accq[4];
#pragma unroll
  for (int j = 0; j < 8; ++j) acc[j] = (f32x4){0.f, 0.f, 0.f, 0.f};
#pragma unroll
  for (int j = 0; j < 4; ++j) accq[j] = (f32x4){0.f, 0.f, 0.f, 0.f};

  float4 ar[4], aq[4];
  bf16x8 br[4];
  // preload chunk 0
#pragma unroll
  for (int i = 0; i < 4; ++i) ar[i] = *(const float4*)(gA + i * 4 * Hh);
#pragma unroll
  for (int i = 0; i < 4; ++i) br[i] = *(const bf16x8*)(gB + i * 8 * Hh);
#pragma unroll
  for (int i = 0; i < 4; ++i)
    aq[i] = *(const float4*)(gQ + (i >> 1) * 32 + (i & 1) * 4);

  for (int kk = 0; kk < NK; ++kk) {
    __syncthreads();  // previous chunk's readers done
    // pack + write chunk kk regs -> LDS
#pragma unroll
    for (int i = 0; i < 4; ++i) {
      bf16x4 p;
      p[0] = f2bf(ar[i].x); p[1] = f2bf(ar[i].y);
      p[2] = f2bf(ar[i].z); p[3] = f2bf(ar[i].w);
      *(bf16x4*)(bufA + aoff + i * 4 * ASTR) = p;
    }
#pragma unroll
    for (int i = 0; i < 4; ++i)
      *(bf16x8*)(bufB + boff + i * 8 * BSTR) = br[i];
    __syncthreads();  // LDS tile visible

    // Build this chunk's q fragments from aq NOW (before prefetch clobbers).
    bf16x8 fq0, fq1;
    fq0[0] = f2bf(aq[0].x); fq0[1] = f2bf(aq[0].y);
    fq0[2] = f2bf(aq[0].z); fq0[3] = f2bf(aq[0].w);
    fq0[4] = f2bf(aq[1].x); fq0[5] = f2bf(aq[1].y);
    fq0[6] = f2bf(aq[1].z); fq0[7] = f2bf(aq[1].w);
    fq1[0] = f2bf(aq[2].x); fq1[1] = f2bf(aq[2].y);
    fq1[2] = f2bf(aq[2].z); fq1[3] = f2bf(aq[2].w);
    fq1[4] = f2bf(aq[3].x); fq1[5] = f2bf(aq[3].y);
    fq1[6] = f2bf(aq[3].z); fq1[7] = f2bf(aq[3].w);

    // issue next-chunk global loads; they have the whole compute phase to land
    {
      const long go = (kk + 1 < NK) ? (long)(kk + 1) * 64 : 0;
#pragma unroll
      for (int i = 0; i < 4; ++i) ar[i] = *(const float4*)(gA + i * 4 * Hh + go);
#pragma unroll
      for (int i = 0; i < 4; ++i) br[i] = *(const bf16x8*)(gB + i * 8 * Hh + go);
#pragma unroll
      for (int i = 0; i < 4; ++i)
        aq[i] = *(const float4*)(gQ + go + (i >> 1) * 32 + (i & 1) * 4);
    }

    // compute chunk kk: doc 16x128 per wave; q 16x64 per wave -- ALL MFMAs
    // unconditional (no guards; see header comment).
#pragma unroll
    for (int ks = 0; ks < 2; ++ks) {
      bf16x8 fa = *(const bf16x8*)(bufA + (w * 16 + lm) * ASTR + ks * 64 + quad * 16);
      const bf16x8 fqk = (ks == 0) ? fq0 : fq1;
#pragma unroll
      for (int j = 0; j < 8; ++j) {
        bf16x8 fb = *(const bf16x8*)(bufB + (j * 16 + lm) * BSTR + ks * 64 + quad * 16);
        acc[j] = __builtin_amdgcn_mfma_f32_16x16x32_bf16(fa, fb, acc[j], 0, 0, 0);
      }
#pragma unroll
      for (int jj = 0; jj < 4; ++jj) {
        bf16x8 fbq = *(const bf16x8*)(bufB + qboff + jj * 16 * BSTR + ks * 64 + quad * 16);
        accq[jj] = __builtin_amdgcn_mfma_f32_16x16x32_bf16(fqk, fbq, accq[jj], 0, 0, 0);
      }
    }
  }

  __syncthreads();  // all staging reads done -> safe to overwrite with dv/lq

  // Epilogue: bias, importance (quad butterfly, fp32), mask -> dvt bf16;
  // every wave writes its 16x64 q sub-tile -> lqt bf16.
  float bc[8], wsv[8];
#pragma unroll
  for (int j = 0; j < 8; ++j) bc[j] = bcomp[j * 16 + lm];
#pragma unroll
  for (int j = 0; j < 8; ++j) wsv[j] = wstop[j * 16 + lm];
  const float bs = bstop[0];

#pragma unroll
  for (int r = 0; r < 4; ++r) {
    const int lrow = w * 16 + quad * 4 + r;  // chunk-local doc row
    float v[8];
#pragma unroll
    for (int j = 0; j < 8; ++j) v[j] = acc[j][r] + bc[j];
    float p = 0.f;
#pragma unroll
    for (int j = 0; j < 8; ++j) p += v[j] * wsv[j];
    p += __shfl_xor(p, 1);
    p += __shfl_xor(p, 2);
    p += __shfl_xor(p, 4);
    p += __shfl_xor(p, 8);
    const float imp = fmaxf(p + bs, 0.f);
    const float scale = imp * (float)dmsk[lrow];
#pragma unroll
    for (int j = 0; j < 8; ++j)
      dvt[lrow * SSTR + j * 16 + lm] = f2bf(v[j] * scale);
  }
  {
    const int qrow0 = wq * 16 + quad * 4;
    float bcq[4];
#pragma unroll
    for (int j = 0; j < 4; ++j) bcq[j] = bcomp[wc * 64 + j * 16 + lm];
#pragma unroll
    for (int r = 0; r < 4; ++r) {
      const int qrow = qrow0 + r;
      const float scale = (float)qmask[b * LQ + qrow];
#pragma unroll
      for (int j = 0; j < 4; ++j)
        lqt[qrow * SSTR + wc * 64 + j * 16 + lm] =
            f2bf((accq[j][r] + bcq[j]) * scale);
    }
  }
  __syncthreads();  // dvt + lqt visible

  // Score phase (R8/R9/R10-proven): thread (qt,kt) owns q rows {qt,qt+16} x
  // doc rows kt*4..+3; bf16x8 LDS reads, shift-convert, fp32 FMA accumulate.
  const int qt = tid & 15;
  const int kt = tid >> 4;
  const int kbase = kt * 4;
  float a[2][4];
#pragma unroll
  for (int qi = 0; qi < 2; ++qi)
#pragma unroll
    for (int ki = 0; ki < 4; ++ki) a[qi][ki] = 0.f;

  for (int c = 0; c < Cc; c += 8) {
    bf16x8 q0 = *(const bf16x8*)&lqt[qt * SSTR + c];
    bf16x8 q1 = *(const bf16x8*)&lqt[(qt + 16) * SSTR + c];
    bf16x8 d0 = *(const bf16x8*)&dvt[(kbase + 0) * SSTR + c];
    bf16x8 d1 = *(const bf16x8*)&dvt[(kbase + 1) * SSTR + c];
    bf16x8 d2 = *(const bf16x8*)&dvt[(kbase + 2) * SSTR + c];
    bf16x8 d3 = *(const bf16x8*)&dvt[(kbase + 3) * SSTR + c];
#pragma unroll
    for (int e = 0; e < 8; ++e) {
      const float f0 = b2f(q0[e]);
      const float f1 = b2f(q1[e]);
      const float g0 = b2f(d0[e]);
      const float g1 = b2f(d1[e]);
      const float g2 = b2f(d2[e]);
      const float g3 = b2f(d3[e]);
      a[0][0] += f0 * g0; a[0][1] += f0 * g1;
      a[0][2] += f0 * g2; a[0][3] += f0 * g3;
      a[1][0] += f1 * g0; a[1][1] += f1 * g1;
      a[1][2] += f1 * g2; a[1][3] += f1 * g3;
    }
  }
  float m0 = -1000.f, m1 = -1000.f;
#pragma unroll
  for (int ki = 0; ki < 4; ++ki) {
    if (dmsk[kbase + ki]) {
      m0 = fmaxf(m0, a[0][ki]);
      m1 = fmaxf(m1, a[1][ki]);
    }
  }
  // Reduce over the wave's 4 kt groups (lanes differ in bits 4-5).
  m0 = fmaxf(m0, __shfl_xor(m0, 16));
  m0 = fmaxf(m0, __shfl_xor(m0, 32));
  m1 = fmaxf(m1, __shfl_xor(m1, 16));
  m1 = fmaxf(m1, __shfl_xor(m1, 32));
  if (lane < 16) {
    pm[w * 32 + lane] = m0;        // q row = lane
    pm[w * 32 + lane + 16] = m1;   // q row = lane + 16
  }
  __syncthreads();
  if (tid < LQ) {
    float mx = fmaxf(fmaxf(pm[tid], pm[32 + tid]),
                     fmaxf(pm[64 + tid], pm[96 + tid]));
    partial[((size_t)b * LQ + tid) * 8 + chunk] = mx;
  }
}

// Finalize: cls dot on raw CLS vectors, max over chunks, masked sum, merge.
__global__ __launch_bounds__(256) void k_final(
    const float* __restrict__ qh, const float* __restrict__ dh,
    const int* __restrict__ qmask, const float* __restrict__ partial,
    const float* __restrict__ merger, float* __restrict__ out) {
  const int b = blockIdx.x;
  const int tid = threadIdx.x;
  __shared__ float red[256];
  __shared__ float clss;
  const float* qc = qh + (size_t)b * LQ * Hh;  // q row 0 = CLS
  const float* dc = dh + (size_t)b * LD * Hh;  // d row 0 = CLS
  float s = 0.f;
  for (int h = tid; h < Hh; h += 256) s += qc[h] * dc[h];
  red[tid] = s;
  __syncthreads();
  for (int off = 128; off > 0; off >>= 1) {
    if (tid < off) red[tid] += red[tid + off];
    __syncthreads();
  }
  if (tid == 0) clss = red[0];
  __syncthreads();
  float t = 0.f;
  if (tid < LQ) {
    const float* pp = partial + ((size_t)b * LQ + tid) * 8;
    float mx = pp[0];
#pragma unroll
    for (int c = 1; c < 8; ++c) mx = fmaxf(mx, pp[c]);
    if (qmask[b * LQ + tid]) t = mx;
  }
  red[tid] = t;
  __syncthreads();
  for (int off = 128; off > 0; off >>= 1) {
    if (tid < off) red[tid] += red[tid + off];
    __syncthreads();
  }
  if (tid == 0) {
    float w = 1.f / (1.f + expf(-merger[0]));
    float cs = clss * w;
    float ts = red[0] * (1.f - w);
    out[b] = cs + ts;        // score
    out[Bb + b] = cs;        // cls_score
    out[2 * Bb + b] = ts;    // term_score
  }
}

extern "C" void kernel_launch(void* const* d_in, const int* in_sizes, int n_in,
                              void* d_out, int out_size, void* d_ws, size_t ws_size,
                              hipStream_t stream) {
  const float* qh  = (const float*)d_in[0];  // (B,LQ,H)
  const float* dh  = (const float*)d_in[1];  // (B,LD,H)
  const int*   qm  = (const int*)d_in[2];    // (B,LQ)
  const int*   dm  = (const int*)d_in[3];    // (B,LD)
  const float* W   = (const float*)d_in[4];  // (H,C)
  const float* bc  = (const float*)d_in[5];  // (C)
  const float* wst = (const float*)d_in[6];  // (C,1)
  const float* bst = (const float*)d_in[7];  // (1)
  const float* mrg = (const float*)d_in[8];  // (1)
  float* out = (float*)d_out;                // 3*B floats

  char* ws = (char*)d_ws;
  short* Wt  = (short*)ws;              // 192 KB bf16 W^T
  float* prt = (float*)(ws + 196608);   // 128 KB partial max

  k_wt<<<(Hh * Cc) / 256, 256, 0, stream>>>(W, Wt);
  k_doc<<<DBLOCKS, 256, 0, stream>>>(dh, qh, Wt, bc, qm, dm, wst, bst, prt);
  k_final<<<Bb, 256, 0, stream>>>(qh, dh, qm, prt, mrg, out);
}